// Round 4
// baseline (2111.632 us; speedup 1.0000x reference)
//
#include <hip/hip_runtime.h>
#include <math.h>

typedef __attribute__((ext_vector_type(8))) short short8;
typedef __attribute__((ext_vector_type(4))) float floatx4;

#define M_TOT 200704            // 64*56*56 token rows
#define SCALE_Q 0.17677669529663687f   // 32^-0.5

__device__ __forceinline__ float u2f(unsigned int u){ return __uint_as_float(u << 16); }
__device__ __forceinline__ unsigned short f2u(float f){
  unsigned int x = __float_as_uint(f);
  x += 0x7fffu + ((x >> 16) & 1u);       // RNE f32->bf16
  return (unsigned short)(x >> 16);
}
// dtype-generic scalar load/store: DT=0 bf16, DT=1 f32
template<int DT> __device__ __forceinline__ float ldS(const void* p, long i){
  if constexpr (DT) return ((const float*)p)[i];
  else return u2f(((const unsigned short*)p)[i]);
}
template<int DT> __device__ __forceinline__ void stS(void* p, long i, float v){
  if constexpr (DT) ((float*)p)[i] = v;
  else ((unsigned short*)p)[i] = f2u(v);
}

// window-layout row m <-> spatial row of x (shift+partition gather; same map is the
// reverse+unshift scatter destination: both are +3 cyclic in each axis)
__device__ __forceinline__ long win_to_x(long m){
  int bb = (int)(m / 3136); int rem = (int)(m % 3136);
  int w = rem / 49, n = rem - w*49;
  int wh = w >> 3, ww = w & 7;
  int i = n / 7, j = n - i*7;
  int p = wh*7 + i + 3; if (p >= 56) p -= 56;
  int q = ww*7 + j + 3; if (q >= 56) q -= 56;
  return (long)bb*3136 + p*56 + q;
}

// ---------------- dtype detector: writes flag (0=bf16, 1=f32) ----------------
// Even-index ushorts of x: bf16 buffer -> N(0,1) bf16 values, exp field in [118,132]
// ~99.8% of the time; f32 buffer -> low mantissa halves, ~6% hit rate.
__global__ void detect_k(const unsigned short* __restrict__ xr, int* __restrict__ flag){
  __shared__ int tot[4];
  int t = threadIdx.x, cnt = 0;
  for (int i = t; i < 4096; i += 256){
    unsigned short u = xr[2*i];
    int e = (u >> 7) & 0xFF;
    if (e >= 118 && e <= 132) cnt++;
  }
  #pragma unroll
  for (int off = 32; off > 0; off >>= 1) cnt += __shfl_xor(cnt, off);
  if ((t & 63) == 0) tot[t >> 6] = cnt;
  __syncthreads();
  if (t == 0) flag[0] = (tot[0]+tot[1]+tot[2]+tot[3] > 2048) ? 0 : 1;
}

// ---------------- MFMA GEMM, weights transposed in-LDS, fused LN/epilogues ----------------
// LNMODE 0: none (A = bf16 scratch); 1: LN + shift/window gather (A = x, dtype DT);
//        2: LN, linear rows (A = d_out, dtype DT)
// EPI 0: +bias, scale cols<192 (QKV)    -> bf16 scratch, stride ostride
// EPI 1: +bias, window-reverse scatter + residual res=x      -> d_out (DT), stride 192
// EPI 2: +bias, exact GELU              -> bf16 scratch, stride ostride
// EPI 3: +bias, residual res=d_out (in-place)                -> d_out (DT), stride 192
template<int KTOT, int LNMODE, int EPI, int DT>
__global__ __launch_bounds__(256) void gemm_kernel(
    const void* __restrict__ A, int astride, long row0g,
    const void* __restrict__ W, int nW,      // W is [KTOT][nW] row-major, dtype DT
    const void* __restrict__ lng, const void* __restrict__ lnb,
    const void* __restrict__ bias, const void* res,
    void* outp, int ostride, const int* __restrict__ flag, int my){
  if (flag[0] != my) return;
  __shared__ __align__(16) unsigned short As[64*200];   // 64 rows x 192 (pad->200)
  __shared__ __align__(16) unsigned short Ws[64*200];   // Ws[c][k] = W[k][n0+c]
  int tid = threadIdx.x;
  int n0 = blockIdx.x*64;
  long lrow0 = (long)blockIdx.y*64;        // local (slab) row base
  int lane = tid & 63, wv = tid >> 6;
  int quad = lane >> 4, l16 = lane & 15;
  constexpr int DTA = (LNMODE == 0) ? 0 : DT;   // A dtype (scratch is always bf16)
  floatx4 acc[4];
  #pragma unroll
  for (int i = 0; i < 4; ++i) acc[i] = (floatx4){0.f,0.f,0.f,0.f};
  constexpr int NK = KTOT/192;
  for (int kc = 0; kc < NK; ++kc){
    if (kc) __syncthreads();
    // ---- stage A tile (64 x 192) into LDS as bf16 ----
    if constexpr (DTA == 0){
      #pragma unroll
      for (int it = 0; it < 6; ++it){      // 1536 16B-chunks / 256 threads
        int idx = tid + it*256;
        int rr = idx / 24, c16 = idx - rr*24;
        long asrc;
        if (LNMODE == 1) asrc = win_to_x(row0g + lrow0 + rr) * 192;
        else             asrc = (lrow0 + rr) * (long)astride + kc*192;
        *(uint4*)(As + rr*200 + c16*8) = *(const uint4*)((const unsigned short*)A + asrc + c16*8);
      }
    } else {
      #pragma unroll
      for (int it = 0; it < 12; ++it){     // 3072 float4-chunks / 256 threads
        int idx = tid + it*256;
        int rr = idx / 48, c4 = idx - rr*48;
        long asrc;
        if (LNMODE == 1) asrc = win_to_x(row0g + lrow0 + rr) * 192;
        else             asrc = (lrow0 + rr) * (long)astride + kc*192;
        float4 f = *(const float4*)((const float*)A + asrc + c4*4);
        ushort4 o; o.x = f2u(f.x); o.y = f2u(f.y); o.z = f2u(f.z); o.w = f2u(f.w);
        *(ushort4*)(As + rr*200 + c4*4) = o;
      }
    }
    // ---- stage+transpose W tile: Ws[c][k] = W[kc*192+k][n0+c] ----
    #pragma unroll
    for (int it = 0; it < 48; ++it){       // 12288 elems / 256 threads
      int idx = tid + it*256;
      int k = idx >> 6, c = idx & 63;
      Ws[c*200 + k] = f2u(ldS<DT>(W, (long)(kc*192 + k)*nW + n0 + c));
    }
    __syncthreads();
    if (LNMODE != 0 && kc == 0){
      // LayerNorm the 64 staged rows in LDS: 4 threads per row, 48 elems each
      int r = tid >> 2, sub = tid & 3;
      unsigned short* rowp = As + r*200 + sub*48;
      float s = 0.f, q2 = 0.f;
      #pragma unroll
      for (int c = 0; c < 48; ++c){ float v = u2f(rowp[c]); s += v; q2 += v*v; }
      s  += __shfl_xor(s, 1);  q2 += __shfl_xor(q2, 1);
      s  += __shfl_xor(s, 2);  q2 += __shfl_xor(q2, 2);
      float mean = s*(1.f/192.f);
      float rs = rsqrtf(q2*(1.f/192.f) - mean*mean + 1e-5f);
      #pragma unroll
      for (int c = 0; c < 48; ++c){
        int col = sub*48 + c;
        float v = (u2f(rowp[c]) - mean)*rs*ldS<DT>(lng, col) + ldS<DT>(lnb, col);
        rowp[c] = f2u(v);
      }
      __syncthreads();
    }
    #pragma unroll
    for (int kk = 0; kk < 6; ++kk){
      short8 af = *(const short8*)(As + (wv*16 + l16)*200 + kk*32 + quad*8);
      #pragma unroll
      for (int nt = 0; nt < 4; ++nt){
        short8 bf = *(const short8*)(Ws + (nt*16 + l16)*200 + kk*32 + quad*8);
        acc[nt] = __builtin_amdgcn_mfma_f32_16x16x32_bf16(af, bf, acc[nt], 0, 0, 0);
      }
    }
  }
  // epilogue: D row = (lane>>4)*4+reg, col = lane&15 (verified gfx950 C/D mapping)
  #pragma unroll
  for (int r = 0; r < 4; ++r){
    long lm = lrow0 + wv*16 + quad*4 + r;
    long drow = 0;
    if (EPI == 1) drow = win_to_x(row0g + lm);
    if (EPI == 3) drow = row0g + lm;
    #pragma unroll
    for (int nt = 0; nt < 4; ++nt){
      int col = n0 + nt*16 + l16;
      float v = acc[nt][r] + ldS<DT>(bias, col);
      if (EPI == 0){
        if (col < 192) v *= SCALE_Q;
        ((unsigned short*)outp)[lm*(long)ostride + col] = f2u(v);
      } else if (EPI == 1){
        v += ldS<DT>(res, drow*192 + col);
        stS<DT>(outp, drow*192 + col, v);
      } else if (EPI == 2){
        v = 0.5f*v*(1.0f + erff(v*0.70710678118654752f));
        ((unsigned short*)outp)[lm*(long)ostride + col] = f2u(v);
      } else {
        v += ldS<DT>(res, drow*192 + col);
        stS<DT>(outp, drow*192 + col, v);
      }
    }
  }
}

// ---------------- window attention: one wave per (window, head), in-place on bf16 qkv ----
template<int DT>
__global__ __launch_bounds__(64) void attn_kernel(unsigned short* __restrict__ qkv,
    const void* __restrict__ rpb, long win0g, const int* __restrict__ flag, int my){
  if (flag[0] != my) return;
  __shared__ float Kf[49*32];
  __shared__ float Vf[49*32];
  __shared__ float biasl[169];
  __shared__ int labs[49];
  int bid = blockIdx.x;
  int wb = bid / 6, head = bid - wb*6;   // wb = local window in slab
  int t = threadIdx.x;
  long base = (long)wb * 49 * 576;
  for (int idx = t; idx < 784; idx += 64){   // 49 rows x 16 bf16-pairs
    int j = idx >> 4, k2 = (idx & 15)*2;
    unsigned int ku = *(const unsigned int*)(qkv + base + j*576 + 192 + head*32 + k2);
    Kf[j*32 + k2] = u2f(ku); Kf[j*32 + k2 + 1] = __uint_as_float(ku & 0xffff0000u);
    unsigned int vu = *(const unsigned int*)(qkv + base + j*576 + 384 + head*32 + k2);
    Vf[j*32 + k2] = u2f(vu); Vf[j*32 + k2 + 1] = __uint_as_float(vu & 0xffff0000u);
  }
  for (int idx = t; idx < 169; idx += 64) biasl[idx] = ldS<DT>(rpb, idx*6 + head);
  if (t < 49){
    int w = (int)((win0g + wb) & 63);     // window index within its image
    int wh = w >> 3, ww = w & 7;
    int i = t / 7, j = t - i*7;
    int p = wh*7 + i, q = ww*7 + j;       // position in shifted frame
    int fp = (p < 49) ? 0 : ((p < 53) ? 1 : 2);
    int fq = (q < 49) ? 0 : ((q < 53) ? 1 : 2);
    labs[t] = fp*3 + fq;
  }
  __syncthreads();
  if (t >= 49) return;
  float qv[32];
  {
    const uint4* qp = (const uint4*)(qkv + base + (long)t*576 + head*32);
    #pragma unroll
    for (int z = 0; z < 4; ++z){
      uint4 u = qp[z];
      qv[z*8+0]=u2f(u.x); qv[z*8+1]=__uint_as_float(u.x & 0xffff0000u);
      qv[z*8+2]=u2f(u.y); qv[z*8+3]=__uint_as_float(u.y & 0xffff0000u);
      qv[z*8+4]=u2f(u.z); qv[z*8+5]=__uint_as_float(u.z & 0xffff0000u);
      qv[z*8+6]=u2f(u.w); qv[z*8+7]=__uint_as_float(u.w & 0xffff0000u);
    }
  }
  int yi = t / 7, xi = t - yi*7;
  int labi = labs[t];
  float s[49];
  #pragma unroll
  for (int yj = 0; yj < 7; ++yj){
    #pragma unroll
    for (int xj = 0; xj < 7; ++xj){
      int j = yj*7 + xj;
      const float* kr = Kf + j*32;
      float a0=0.f,a1=0.f,a2=0.f,a3=0.f;
      #pragma unroll
      for (int k = 0; k < 32; k += 4){
        a0 = fmaf(qv[k],   kr[k],   a0);
        a1 = fmaf(qv[k+1], kr[k+1], a1);
        a2 = fmaf(qv[k+2], kr[k+2], a2);
        a3 = fmaf(qv[k+3], kr[k+3], a3);
      }
      float sv = (a0+a1)+(a2+a3);
      sv += biasl[(yi - yj + 6)*13 + (xi - xj + 6)];
      sv += (labs[j] == labi) ? 0.0f : -100.0f;
      s[j] = sv;
    }
  }
  float mx = s[0];
  #pragma unroll
  for (int j = 1; j < 49; ++j) mx = fmaxf(mx, s[j]);
  float l = 0.f;
  #pragma unroll
  for (int j = 0; j < 49; ++j){ float e = __expf(s[j]-mx); s[j] = e; l += e; }
  float inv = 1.0f / l;
  float o[32];
  #pragma unroll
  for (int k = 0; k < 32; ++k) o[k] = 0.f;
  #pragma unroll
  for (int j = 0; j < 49; ++j){
    float pj = s[j];
    const float* vr = Vf + j*32;
    #pragma unroll
    for (int k = 0; k < 32; ++k) o[k] = fmaf(pj, vr[k], o[k]);
  }
  // write over own q-slice (block-local, race-free)
  unsigned short* op = qkv + base + (long)t*576 + head*32;
  uint4 ov[4];
  unsigned int* ow = (unsigned int*)ov;
  #pragma unroll
  for (int k2 = 0; k2 < 16; ++k2){
    ow[k2] = (unsigned int)f2u(o[2*k2]*inv) | ((unsigned int)f2u(o[2*k2+1]*inv) << 16);
  }
  uint4* o4 = (uint4*)op;
  #pragma unroll
  for (int z = 0; z < 4; ++z) o4[z] = ov[z];
}

template<int DT>
static void run_path(const void* x, const void* ln1_g, const void* ln1_b,
                     const void* qkv_w, const void* qkv_b, const void* proj_w,
                     const void* proj_b, const void* rpb, const void* ln2_g,
                     const void* ln2_b, const void* w1, const void* b1,
                     const void* w2, const void* b2, void* out,
                     unsigned short* buf, long Sa, int nA, long Sm, int nM,
                     const int* flag, hipStream_t stream){
  // ---- attention branch: x -> out (= x + attn(ln1(x))) ----
  for (int s = 0; s < nA; ++s){
    long r0 = (long)s*Sa;
    gemm_kernel<192,1,0,DT><<<dim3(9, Sa/64), 256, 0, stream>>>(
        x, 192, r0, qkv_w, 576, ln1_g, ln1_b, qkv_b, nullptr, buf, 576, flag, DT);
    attn_kernel<DT><<<(int)(Sa/49)*6, 64, 0, stream>>>(buf, rpb, r0/49, flag, DT);
    gemm_kernel<192,0,1,DT><<<dim3(3, Sa/64), 256, 0, stream>>>(
        buf, 576, r0, proj_w, 192, nullptr, nullptr, proj_b, x, out, 192, flag, DT);
  }
  // ---- MLP branch: out -> out (= x2 + mlp(ln2(x2))) ----
  for (int s = 0; s < nM; ++s){
    long r0 = (long)s*Sm;
    const void* a2 = (DT == 1) ? (const void*)((const float*)out + r0*192)
                               : (const void*)((const unsigned short*)out + r0*192);
    gemm_kernel<192,2,2,DT><<<dim3(12, Sm/64), 256, 0, stream>>>(
        a2, 192, r0, w1, 768, ln2_g, ln2_b, b1, nullptr, buf, 768, flag, DT);
    gemm_kernel<768,0,3,DT><<<dim3(3, Sm/64), 256, 0, stream>>>(
        buf, 768, r0, w2, 192, nullptr, nullptr, b2, out, out, 192, flag, DT);
  }
}

extern "C" void kernel_launch(void* const* d_in, const int* in_sizes, int n_in,
                              void* d_out, int out_size, void* d_ws, size_t ws_size,
                              hipStream_t stream){
  const void* x     = d_in[0];
  const void* ln1_g = d_in[1];
  const void* ln1_b = d_in[2];
  const void* qkv_w = d_in[3];
  const void* qkv_b = d_in[4];
  const void* proj_w= d_in[5];
  const void* proj_b= d_in[6];
  const void* rpb   = d_in[7];
  const void* ln2_g = d_in[8];
  const void* ln2_b = d_in[9];
  const void* w1    = d_in[10];
  const void* b1    = d_in[11];
  const void* w2    = d_in[12];
  const void* b2    = d_in[13];

  int* flag = (int*)d_ws;                                  // 256 B reserved
  unsigned short* buf = (unsigned short*)((char*)d_ws + 256);
  size_t bufb = ws_size > 256 ? ws_size - 256 : 0;

  // --- slab sizing (depends only on constant ws_size -> identical every call) ---
  int da = 64;
  while (da > 1 && (size_t)3136*(size_t)da*1152ULL > bufb) da >>= 1;
  long Sa = 3136L*da;             // attention slab rows (whole images); qkv bytes = Sa*1152
  int nA = 64/da;
  static const long smlist[] = {200704,100352,50176,25088,12544,6272,3136,1792,1024,512,448,256,128,64};
  long Sm = 64;
  for (int i = 0; i < 14; ++i) if ((size_t)smlist[i]*1536ULL <= bufb){ Sm = smlist[i]; break; }
  int nM = (int)(M_TOT / Sm);

  detect_k<<<1, 256, 0, stream>>>((const unsigned short*)x, flag);

  run_path<0>(x, ln1_g, ln1_b, qkv_w, qkv_b, proj_w, proj_b, rpb, ln2_g, ln2_b,
              w1, b1, w2, b2, d_out, buf, Sa, nA, Sm, nM, flag, stream);
  run_path<1>(x, ln1_g, ln1_b, qkv_w, qkv_b, proj_w, proj_b, rpb, ln2_g, ln2_b,
              w1, b1, w2, b2, d_out, buf, Sa, nA, Sm, nM, flag, stream);
}

// Round 5
// 1695.546 us; speedup vs baseline: 1.2454x; 1.2454x over previous
//
#include <hip/hip_runtime.h>
#include <math.h>

typedef __attribute__((ext_vector_type(8))) short short8;
typedef __attribute__((ext_vector_type(4))) float floatx4;

#define M_TOT 200704            // 64*56*56 token rows
#define SCALE_Q 0.17677669529663687f   // 32^-0.5

__device__ __forceinline__ float u2f(unsigned int u){ return __uint_as_float(u << 16); }
__device__ __forceinline__ unsigned short f2u(float f){
  unsigned int x = __float_as_uint(f);
  x += 0x7fffu + ((x >> 16) & 1u);       // RNE f32->bf16
  return (unsigned short)(x >> 16);
}

// window-layout row m -> spatial row of x (shift+partition gather; same map is the
// reverse+unshift scatter destination: both are +3 cyclic in each axis)
__device__ __forceinline__ int win_to_x(int m){
  int bb = m / 3136; int rem = m - bb*3136;
  int w = rem / 49, n = rem - w*49;
  int wh = w >> 3, ww = w & 7;
  int i = n / 7, j = n - i*7;
  int p = wh*7 + i + 3; if (p >= 56) p -= 56;
  int q = ww*7 + j + 3; if (q >= 56) q -= 56;
  return bb*3136 + p*56 + q;
}

// ---------------- prep: f32 W[K][N] -> bf16 Wt[N][K]  ----------------
__global__ void conv_wt(const float* __restrict__ in, unsigned short* __restrict__ out,
                        int K, int N){
  int t = blockIdx.x*256 + threadIdx.x;
  if (t < K*N){ int k = t / N, n = t - k*N; out[n*K + k] = f2u(in[t]); }
}
// ---------------- prep: row gather/scatter map ----------------
__global__ void rowmap_k(int* __restrict__ map){
  int t = blockIdx.x*256 + threadIdx.x;
  if (t < M_TOT) map[t] = win_to_x(t);
}

// ---------------- MFMA GEMM, bf16 pre-transposed weights, fused LN/epilogues ----
// LNMODE 0: none (A bf16 scratch, stride astride)
//        1: LN + gather via rowmap (A = x, f32, stride 192)
//        2: LN, linear rows (A = d_out, f32, stride 192)
// EPI 0: +bias, scale cols<192 (QKV)    -> bf16 scratch, stride ostride
// EPI 1: +bias, scatter via rowmap + residual res=x (f32) -> d_out f32
// EPI 2: +bias, exact GELU              -> bf16 scratch, stride ostride
// EPI 3: +bias, residual res=out (in-place, f32)          -> d_out f32
template<int KTOT, int LNMODE, int EPI>
__global__ __launch_bounds__(256) void gemm_kernel(
    const void* __restrict__ A, int astride, long row0g,
    const unsigned short* __restrict__ Wt,     // [nW][KTOT] bf16
    const float* __restrict__ lng, const float* __restrict__ lnb,
    const float* __restrict__ bias, const float* __restrict__ res,
    void* __restrict__ outp, int ostride, const int* __restrict__ rowmap){
  __shared__ __align__(16) unsigned short As[64*200];   // 64 rows x 192 (pad->200)
  __shared__ __align__(16) unsigned short Ws[64*200];
  int tid = threadIdx.x;
  int n0 = blockIdx.x*64;
  long lrow0 = (long)blockIdx.y*64;        // local (slab) row base
  int lane = tid & 63, wv = tid >> 6;
  int quad = lane >> 4, l16 = lane & 15;
  floatx4 acc[4];
  #pragma unroll
  for (int i = 0; i < 4; ++i) acc[i] = (floatx4){0.f,0.f,0.f,0.f};
  constexpr int NK = KTOT/192;
  for (int kc = 0; kc < NK; ++kc){
    if (kc) __syncthreads();
    // ---- stage A tile (64 x 192) into LDS as bf16 ----
    if constexpr (LNMODE == 0){
      #pragma unroll
      for (int it = 0; it < 6; ++it){      // 1536 16B-chunks / 256 threads
        int idx = tid + it*256;
        int rr = idx / 24, c16 = idx - rr*24;
        long asrc = (lrow0 + rr) * (long)astride + kc*192;
        *(uint4*)(As + rr*200 + c16*8) = *(const uint4*)((const unsigned short*)A + asrc + c16*8);
      }
    } else {
      #pragma unroll
      for (int it = 0; it < 12; ++it){     // 3072 float4-chunks / 256 threads
        int idx = tid + it*256;
        int rr = idx / 48, c4 = idx - rr*48;
        long srow = (LNMODE == 1) ? (long)rowmap[row0g + lrow0 + rr] : (row0g + lrow0 + rr);
        float4 f = *(const float4*)((const float*)A + srow*192 + c4*4);
        ushort4 o; o.x = f2u(f.x); o.y = f2u(f.y); o.z = f2u(f.z); o.w = f2u(f.w);
        *(ushort4*)(As + rr*200 + c4*4) = o;
      }
    }
    // ---- stage W tile: Ws[c][k] = Wt[n0+c][kc*192+k], 16B copies ----
    #pragma unroll
    for (int it = 0; it < 6; ++it){
      int idx = tid + it*256;
      int rr = idx / 24, c16 = idx - rr*24;
      *(uint4*)(Ws + rr*200 + c16*8) = *(const uint4*)(Wt + (long)(n0+rr)*KTOT + kc*192 + c16*8);
    }
    __syncthreads();
    if (LNMODE != 0 && kc == 0){
      // LayerNorm the 64 staged rows in LDS: 4 threads per row, 48 elems each
      int r = tid >> 2, sub = tid & 3;
      unsigned short* rowp = As + r*200 + sub*48;
      float s = 0.f, q2 = 0.f;
      #pragma unroll
      for (int c = 0; c < 48; ++c){ float v = u2f(rowp[c]); s += v; q2 += v*v; }
      s  += __shfl_xor(s, 1);  q2 += __shfl_xor(q2, 1);
      s  += __shfl_xor(s, 2);  q2 += __shfl_xor(q2, 2);
      float mean = s*(1.f/192.f);
      float rs = rsqrtf(q2*(1.f/192.f) - mean*mean + 1e-5f);
      #pragma unroll
      for (int c = 0; c < 48; ++c){
        int col = sub*48 + c;
        float v = (u2f(rowp[c]) - mean)*rs*lng[col] + lnb[col];
        rowp[c] = f2u(v);
      }
      __syncthreads();
    }
    #pragma unroll
    for (int kk = 0; kk < 6; ++kk){
      short8 af = *(const short8*)(As + (wv*16 + l16)*200 + kk*32 + quad*8);
      #pragma unroll
      for (int nt = 0; nt < 4; ++nt){
        short8 bf = *(const short8*)(Ws + (nt*16 + l16)*200 + kk*32 + quad*8);
        acc[nt] = __builtin_amdgcn_mfma_f32_16x16x32_bf16(af, bf, acc[nt], 0, 0, 0);
      }
    }
  }
  // epilogue: D row = (lane>>4)*4+reg, col = lane&15 (verified gfx950 C/D mapping)
  #pragma unroll
  for (int r = 0; r < 4; ++r){
    long lm = lrow0 + wv*16 + quad*4 + r;
    long drow = 0;
    if (EPI == 1) drow = rowmap[row0g + lm];
    if (EPI == 3) drow = row0g + lm;
    #pragma unroll
    for (int nt = 0; nt < 4; ++nt){
      int col = n0 + nt*16 + l16;
      float v = acc[nt][r] + bias[col];
      if (EPI == 0){
        if (col < 192) v *= SCALE_Q;
        ((unsigned short*)outp)[lm*(long)ostride + col] = f2u(v);
      } else if (EPI == 1){
        v += res[drow*192 + col];
        ((float*)outp)[drow*192 + col] = v;
      } else if (EPI == 2){
        v = 0.5f*v*(1.0f + erff(v*0.70710678118654752f));
        ((unsigned short*)outp)[lm*(long)ostride + col] = f2u(v);
      } else {
        v += res[drow*192 + col];
        ((float*)outp)[drow*192 + col] = v;
      }
    }
  }
}

// ---------------- window attention: one wave per (window, head), in-place on bf16 qkv ----
__global__ __launch_bounds__(64) void attn_kernel(unsigned short* __restrict__ qkv,
    const float* __restrict__ rpb, long win0g){
  __shared__ float Kf[49*32];
  __shared__ float Vf[49*32];
  __shared__ float biasl[169];
  __shared__ int labs[49];
  int bid = blockIdx.x;
  int wb = bid / 6, head = bid - wb*6;   // wb = local window in slab
  int t = threadIdx.x;
  long base = (long)wb * 49 * 576;
  for (int idx = t; idx < 784; idx += 64){   // 49 rows x 16 bf16-pairs
    int j = idx >> 4, k2 = (idx & 15)*2;
    unsigned int ku = *(const unsigned int*)(qkv + base + j*576 + 192 + head*32 + k2);
    Kf[j*32 + k2] = u2f(ku); Kf[j*32 + k2 + 1] = __uint_as_float(ku & 0xffff0000u);
    unsigned int vu = *(const unsigned int*)(qkv + base + j*576 + 384 + head*32 + k2);
    Vf[j*32 + k2] = u2f(vu); Vf[j*32 + k2 + 1] = __uint_as_float(vu & 0xffff0000u);
  }
  for (int idx = t; idx < 169; idx += 64) biasl[idx] = rpb[idx*6 + head];
  if (t < 49){
    int w = (int)((win0g + wb) & 63);     // window index within its image
    int wh = w >> 3, ww = w & 7;
    int i = t / 7, j = t - i*7;
    int p = wh*7 + i, q = ww*7 + j;       // position in shifted frame
    int fp = (p < 49) ? 0 : ((p < 53) ? 1 : 2);
    int fq = (q < 49) ? 0 : ((q < 53) ? 1 : 2);
    labs[t] = fp*3 + fq;
  }
  __syncthreads();
  if (t >= 49) return;
  float qv[32];
  {
    const uint4* qp = (const uint4*)(qkv + base + (long)t*576 + head*32);
    #pragma unroll
    for (int z = 0; z < 4; ++z){
      uint4 u = qp[z];
      qv[z*8+0]=u2f(u.x); qv[z*8+1]=__uint_as_float(u.x & 0xffff0000u);
      qv[z*8+2]=u2f(u.y); qv[z*8+3]=__uint_as_float(u.y & 0xffff0000u);
      qv[z*8+4]=u2f(u.z); qv[z*8+5]=__uint_as_float(u.z & 0xffff0000u);
      qv[z*8+6]=u2f(u.w); qv[z*8+7]=__uint_as_float(u.w & 0xffff0000u);
    }
  }
  int yi = t / 7, xi = t - yi*7;
  int labi = labs[t];
  float s[49];
  #pragma unroll
  for (int yj = 0; yj < 7; ++yj){
    #pragma unroll
    for (int xj = 0; xj < 7; ++xj){
      int j = yj*7 + xj;
      const float* kr = Kf + j*32;
      float a0=0.f,a1=0.f,a2=0.f,a3=0.f;
      #pragma unroll
      for (int k = 0; k < 32; k += 4){
        a0 = fmaf(qv[k],   kr[k],   a0);
        a1 = fmaf(qv[k+1], kr[k+1], a1);
        a2 = fmaf(qv[k+2], kr[k+2], a2);
        a3 = fmaf(qv[k+3], kr[k+3], a3);
      }
      float sv = (a0+a1)+(a2+a3);
      sv += biasl[(yi - yj + 6)*13 + (xi - xj + 6)];
      sv += (labs[j] == labi) ? 0.0f : -100.0f;
      s[j] = sv;
    }
  }
  float mx = s[0];
  #pragma unroll
  for (int j = 1; j < 49; ++j) mx = fmaxf(mx, s[j]);
  float l = 0.f;
  #pragma unroll
  for (int j = 0; j < 49; ++j){ float e = __expf(s[j]-mx); s[j] = e; l += e; }
  float inv = 1.0f / l;
  float o[32];
  #pragma unroll
  for (int k = 0; k < 32; ++k) o[k] = 0.f;
  #pragma unroll
  for (int j = 0; j < 49; ++j){
    float pj = s[j];
    const float* vr = Vf + j*32;
    #pragma unroll
    for (int k = 0; k < 32; ++k) o[k] = fmaf(pj, vr[k], o[k]);
  }
  // write over own q-slice (block-local, race-free)
  unsigned short* op = qkv + base + (long)t*576 + head*32;
  uint4 ov[4];
  unsigned int* ow = (unsigned int*)ov;
  #pragma unroll
  for (int k2 = 0; k2 < 16; ++k2){
    ow[k2] = (unsigned int)f2u(o[2*k2]*inv) | ((unsigned int)f2u(o[2*k2+1]*inv) << 16);
  }
  uint4* o4 = (uint4*)op;
  #pragma unroll
  for (int z = 0; z < 4; ++z) o4[z] = ov[z];
}

extern "C" void kernel_launch(void* const* d_in, const int* in_sizes, int n_in,
                              void* d_out, int out_size, void* d_ws, size_t ws_size,
                              hipStream_t stream){
  const float* x     = (const float*)d_in[0];
  const float* ln1_g = (const float*)d_in[1];
  const float* ln1_b = (const float*)d_in[2];
  const float* qkv_w = (const float*)d_in[3];
  const float* qkv_b = (const float*)d_in[4];
  const float* proj_w= (const float*)d_in[5];
  const float* proj_b= (const float*)d_in[6];
  const float* rpb   = (const float*)d_in[7];
  const float* ln2_g = (const float*)d_in[8];
  const float* ln2_b = (const float*)d_in[9];
  const float* w1    = (const float*)d_in[10];
  const float* b1    = (const float*)d_in[11];
  const float* w2    = (const float*)d_in[12];
  const float* b2    = (const float*)d_in[13];
  float* out = (float*)d_out;

  // ws layout: bf16 transposed weights | rowmap | activation scratch
  unsigned short* wt_qkv  = (unsigned short*)d_ws;        // 576 x 192
  unsigned short* wt_proj = wt_qkv  + 576*192;            // 192 x 192
  unsigned short* wt_m1   = wt_proj + 192*192;            // 768 x 192
  unsigned short* wt_m2   = wt_m1   + 768*192;            // 192 x 768
  int* rowmap = (int*)(wt_m2 + 192*768);                  // M_TOT ints
  unsigned short* buf = (unsigned short*)(rowmap + M_TOT);
  size_t ovh = (size_t)(576*192 + 192*192 + 768*192 + 192*768)*2 + (size_t)M_TOT*4;
  size_t bufb = ws_size > ovh ? ws_size - ovh : 0;

  // --- slab sizing (depends only on constant ws_size -> identical every call) ---
  int da = 64;
  while (da > 1 && (size_t)3136*(size_t)da*1152ULL > bufb) da >>= 1;
  long Sa = 3136L*da;             // attention slab rows (whole images); qkv bytes = Sa*1152
  int nA = 64/da;
  static const long smlist[] = {200704,100352,50176,25088,12544,6272,3136,1792,1024,512,448,256,128,64};
  long Sm = 64;
  for (int i = 0; i < 14; ++i) if ((size_t)smlist[i]*1536ULL <= bufb){ Sm = smlist[i]; break; }
  int nM = (int)(M_TOT / Sm);

  // ---- prep: weights -> bf16 transposed; row gather map ----
  conv_wt<<<(192*576+255)/256, 256, 0, stream>>>(qkv_w, wt_qkv, 192, 576);
  conv_wt<<<(192*192+255)/256, 256, 0, stream>>>(proj_w, wt_proj, 192, 192);
  conv_wt<<<(192*768+255)/256, 256, 0, stream>>>(w1, wt_m1, 192, 768);
  conv_wt<<<(768*192+255)/256, 256, 0, stream>>>(w2, wt_m2, 768, 192);
  rowmap_k<<<(M_TOT+255)/256, 256, 0, stream>>>(rowmap);

  // ---- attention branch: x -> out (= x + attn(ln1(x))) ----
  for (int s = 0; s < nA; ++s){
    long r0 = (long)s*Sa;
    gemm_kernel<192,1,0><<<dim3(9, Sa/64), 256, 0, stream>>>(
        x, 192, r0, wt_qkv, ln1_g, ln1_b, qkv_b, nullptr, buf, 576, rowmap);
    attn_kernel<<<(int)(Sa/49)*6, 64, 0, stream>>>(buf, rpb, r0/49);
    gemm_kernel<192,0,1><<<dim3(3, Sa/64), 256, 0, stream>>>(
        buf, 576, r0, wt_proj, nullptr, nullptr, proj_b, x, out, 192, rowmap);
  }

  // ---- MLP branch: out -> out (= x2 + mlp(ln2(x2))) ----
  for (int s = 0; s < nM; ++s){
    long r0 = (long)s*Sm;
    gemm_kernel<192,2,2><<<dim3(12, Sm/64), 256, 0, stream>>>(
        out + r0*192, 192, r0, wt_m1, ln2_g, ln2_b, b1, nullptr, buf, 768, rowmap);
    gemm_kernel<768,0,3><<<dim3(3, Sm/64), 256, 0, stream>>>(
        buf, 768, r0, wt_m2, nullptr, nullptr, b2, out, out, 192, rowmap);
  }
}